// Round 7
// baseline (70.055 us; speedup 1.0000x reference)
//
#include <hip/hip_runtime.h>
#include <math.h>

// Problem constants (from reference setup_inputs)
#define N_  2
#define C_  64
#define S_  4
#define H_  64
#define W_  44
#define HW_       (H_ * W_)          // 2816
#define CH_STRIDE (S_ * HW_)         // 11264 elements between channels
#define NSTRIDE   (C_ * S_ * HW_)    // 720896 elements between n-batches

typedef _Float16 h2 __attribute__((ext_vector_type(2)));
typedef _Float16 h8 __attribute__((ext_vector_type(8)));

#if defined(__has_builtin)
#  if __has_builtin(__builtin_amdgcn_fdot2)
#    define FDOT2(a, b, c) __builtin_amdgcn_fdot2((a), (b), (c), false)
#  endif
#endif
#ifndef FDOT2
#  define FDOT2(a, b, c) ((float)(a).x * (float)(b).x + (float)(a).y * (float)(b).y + (c))
#endif

// Round 7: same dataflow as round 6, but wave = (dy, channel-half) so the
// 512-block grid carries 14 waves/block -> 28 waves/CU (was 14). Per-CU
// VMEM/LDS/VALU totals unchanged; this purely doubles latency hiding.
//  - wave w (0..13): dy = w%7 row, half = w/7 -> channels [half*32, +32)
//  - stage: 32 f1 loads -> f16 pack -> 4 ds_write_b128 into row slab
//  - f0 loads issued AFTER f1 loads (vmcnt is in-order: staging waits
//    don't drain them; they fly across the barrier)
//  - compute: 28 tap ds_read_b128 + 112 v_dot2_f32_f16
//  - corr: low-half waves write, high-half waves add (2 barriers)
__global__ __launch_bounds__(896) void flow_kernel(
    const float* __restrict__ f0,
    const float* __restrict__ f1,
    float* __restrict__ out)
{
    const int lane = threadIdx.x & 63;
    const int w    = threadIdx.x >> 6;          // 0..13
    const int dy   = (w < 7) ? w : (w - 7);
    const int half = (w < 7) ? 0 : 1;

    // b = blockIdx & 7: batch pinned per XCD slot for L2 locality
    const int b = blockIdx.x & 7;
    const int y = blockIdx.x >> 3;
    const int n_idx = b >> 2;
    const int s_idx = b & 3;
    const int base  = n_idx * NSTRIDE + s_idx * HW_;

    // 7 row slabs (f16 [c8 0..7][x<44][8ch] = 5632 B each) + corr f32 [44][49]
    __shared__ __align__(16) char lds_raw[7 * 5632 + W_ * 49 * 4];  // 48 KB
    _Float16* lds_h = (_Float16*)lds_raw;
    float (*corr)[49] = (float(*)[49])(lds_raw + 7 * 5632);

    const int x   = lane;
    const int xe  = min(x, W_ - 1);             // clamp idle lanes
    const int row = y + dy - 3;
    const bool row_ok = (row >= 0) && (row < H_);

    float acc[7] = {0.f, 0.f, 0.f, 0.f, 0.f, 0.f, 0.f};

    _Float16* slab = lds_h + dy * 2816;         // this dy's row slab
    const int ch0 = half * 32;

    float a[32];                                // f0 values (post-barrier use)

    if (row_ok) {
        // ---- issue f1 loads first (staging waits only cover these) ----
        const float* f1p = f1 + base + row * W_ + xe + (size_t)ch0 * CH_STRIDE;
        float v[32];
        #pragma unroll
        for (int j = 0; j < 32; ++j) v[j] = f1p[(size_t)j * CH_STRIDE];

        // ---- then f0 loads: stay outstanding across pack/write/barrier ----
        const float* f0p = f0 + base + y * W_ + xe + (size_t)ch0 * CH_STRIDE;
        #pragma unroll
        for (int j = 0; j < 32; ++j) a[j] = f0p[(size_t)j * CH_STRIDE];

        // pack + stage 4 c8-chunks of this half-row
        if (x < W_) {
            #pragma unroll
            for (int c8l = 0; c8l < 4; ++c8l) {
                h8 pk;
                #pragma unroll
                for (int j = 0; j < 8; ++j) pk[j] = (_Float16)v[c8l * 8 + j];
                *(h8*)&slab[((4 * half + c8l) * W_ + x) * 8] = pk;  // ds_write_b128
            }
        }
    }

    __syncthreads();   // all 7 rows staged (both halves)

    if (row_ok) {
        h2 a2[16];
        #pragma unroll
        for (int j = 0; j < 16; ++j) {
            h2 t; t.x = (_Float16)a[2 * j]; t.y = (_Float16)a[2 * j + 1];
            a2[j] = t;
        }
        int xt[7];
        #pragma unroll
        for (int dx = 0; dx < 7; ++dx)
            xt[dx] = min(max(x + dx - 3, 0), W_ - 1);     // clamped tap col

        #pragma unroll
        for (int c8l = 0; c8l < 4; ++c8l) {
            const _Float16* rp = &slab[(4 * half + c8l) * W_ * 8];
            #pragma unroll
            for (int dx = 0; dx < 7; ++dx) {
                const h8 t = *(const h8*)&rp[xt[dx] * 8]; // ds_read_b128
                h2 t01, t23, t45, t67;
                t01.x = t[0]; t01.y = t[1];
                t23.x = t[2]; t23.y = t[3];
                t45.x = t[4]; t45.y = t[5];
                t67.x = t[6]; t67.y = t[7];
                float s = acc[dx];
                s = FDOT2(a2[c8l * 4 + 0], t01, s);
                s = FDOT2(a2[c8l * 4 + 1], t23, s);
                s = FDOT2(a2[c8l * 4 + 2], t45, s);
                s = FDOT2(a2[c8l * 4 + 3], t67, s);
                acc[dx] = s;
            }
        }
    }

    // two-step corr combine: low half writes, high half accumulates
    if (half == 0 && row_ok && x < W_) {
        #pragma unroll
        for (int dx = 0; dx < 7; ++dx)
            corr[x][dy * 7 + dx] = acc[dx] * 0.125f;      // 1/sqrt(64)
    }
    __syncthreads();
    if (half == 1 && row_ok && x < W_) {
        #pragma unroll
        for (int dx = 0; dx < 7; ++dx)
            corr[x][dy * 7 + dx] += acc[dx] * 0.125f;
    }
    __syncthreads();

    // Wave 0: per-lane softmax over 49 taps + expected flow (registers only)
    if (w == 0) {
        float c[49];
        float m = -1e30f;
        #pragma unroll
        for (int k = 0; k < 49; ++k) {
            const int kdy = k / 7, kdx = k % 7;
            const int col = x + kdx - 3;
            const int rr  = y + kdy - 3;
            const bool ok = (col >= 0) && (col < W_) && (rr >= 0) && (rr < H_);
            const float v = ok ? corr[xe][k] : -1e30f;    // mask garbage taps
            c[k] = v;
            m = fmaxf(m, v);
        }
        float S = 0.0f, Sx = 0.0f, Sy = 0.0f;
        #pragma unroll
        for (int k = 0; k < 49; ++k) {
            const float e = __expf(c[k] - m);             // -1e30 -> 0
            S  += e;
            Sx += e * (float)(k % 7 - 3);
            Sy += e * (float)(k / 7 - 3);
        }
        if (lane < W_) {
            const float inv = 1.0f / S;
            // out layout: (n, 2, s, h, w)
            const int ob = (n_idx * 2) * S_ * HW_ + s_idx * HW_ + y * W_ + lane;
            out[ob]            = Sx * inv;                // flow x
            out[ob + S_ * HW_] = Sy * inv;                // flow y
        }
    }
}

extern "C" void kernel_launch(void* const* d_in, const int* in_sizes, int n_in,
                              void* d_out, int out_size, void* d_ws, size_t ws_size,
                              hipStream_t stream) {
    const float* f0 = (const float*)d_in[0];
    const float* f1 = (const float*)d_in[1];
    float* out = (float*)d_out;

    flow_kernel<<<8 * H_, 896, 0, stream>>>(f0, f1, out);  // 512 blocks x 14 waves
}

// Round 8
// 66.219 us; speedup vs baseline: 1.0579x; 1.0579x over previous
//
#include <hip/hip_runtime.h>
#include <math.h>

// Problem constants (from reference setup_inputs)
#define N_  2
#define C_  64
#define S_  4
#define H_  64
#define W_  44
#define HW_       (H_ * W_)          // 2816
#define CH_STRIDE (S_ * HW_)         // 11264 elements between channels
#define NSTRIDE   (C_ * S_ * HW_)    // 720896 elements between n-batches

typedef _Float16 h2 __attribute__((ext_vector_type(2)));
typedef _Float16 h8 __attribute__((ext_vector_type(8)));

#if defined(__has_builtin)
#  if __has_builtin(__builtin_amdgcn_fdot2)
#    define FDOT2(a, b, c) __builtin_amdgcn_fdot2((a), (b), (c), false)
#  endif
#endif
#ifndef FDOT2
#  define FDOT2(a, b, c) ((float)(a).x * (float)(b).x + (float)(a).y * (float)(b).y + (c))
#endif

// Round 8: one global round-trip per wave.
// Block = (b, y), 512 threads = 8 waves, lane = x.
//   waves 0..6: stage f1 row y+w-3 (ALL 64 loads issued before any wait,
//               then pack f16 -> 8 ds_write_b128 into slab w)
//   wave 7:     stage f0 row y identically into slab 7 (de-dups the 7x
//               redundant f0 loads of rounds 5-7)
// ONE barrier, then the dot phase is LDS-only: per c8, 1 f0-frag b128 +
// 7 tap b128 + 16 v_dot2_f32_f16. Each f1 wave owns all 64 channels of its
// dy -> corr written in one disjoint step. 2 barriers total.
// LDS: 8 slabs x 5632 B + corr 8624 B = 53.7 KB -> 2 blocks/CU (= grid).
__global__ __launch_bounds__(512) void flow_kernel(
    const float* __restrict__ f0,
    const float* __restrict__ f1,
    float* __restrict__ out)
{
    const int lane = threadIdx.x & 63;
    const int w    = threadIdx.x >> 6;          // 0..7

    // b = blockIdx & 7: batch pinned per XCD slot for L2 locality
    const int b = blockIdx.x & 7;
    const int y = blockIdx.x >> 3;
    const int n_idx = b >> 2;
    const int s_idx = b & 3;
    const int base  = n_idx * NSTRIDE + s_idx * HW_;

    // slabs: [w][c8][x][8ch] f16; slab 7 = f0. corr separate (no alias).
    __shared__ __align__(16) _Float16 slabs[8 * 8 * W_ * 8];   // 45056 B
    __shared__ float corr[W_][49];                             // 8624 B

    const int x  = lane;
    const int xe = min(x, W_ - 1);              // clamp idle lanes

    // staging row: waves 0..6 -> f1 row y+w-3; wave 7 -> f0 row y
    const int  r      = (w == 7) ? y : (y + w - 3);
    const bool stg_ok = (r >= 0) && (r < H_);
    const float* src  = (w == 7) ? f0 : f1;

    if (stg_ok) {
        const float* p = src + base + r * W_ + xe;
        float v[64];
        #pragma unroll
        for (int j = 0; j < 64; ++j)            // all 64 issued, no waits between
            v[j] = p[(size_t)j * CH_STRIDE];
        if (x < W_) {
            #pragma unroll
            for (int c8 = 0; c8 < 8; ++c8) {
                h8 pk;
                #pragma unroll
                for (int j = 0; j < 8; ++j) pk[j] = (_Float16)v[c8 * 8 + j];
                *(h8*)&slabs[((w * 8 + c8) * W_ + x) * 8] = pk;  // ds_write_b128
            }
        }
    }

    __syncthreads();   // all rows + f0 staged

    // ---- dot phase: LDS-only (waves 0..6 with valid rows) ----
    if (w < 7 && stg_ok) {
        float acc[7] = {0.f, 0.f, 0.f, 0.f, 0.f, 0.f, 0.f};
        int xt[7];
        #pragma unroll
        for (int dx = 0; dx < 7; ++dx)
            xt[dx] = min(max(x + dx - 3, 0), W_ - 1);   // clamped tap col

        const _Float16* f0slab = &slabs[(7 * 8) * W_ * 8];
        const _Float16* myslab = &slabs[(w * 8) * W_ * 8];

        #pragma unroll
        for (int c8 = 0; c8 < 8; ++c8) {
            const h8 af = *(const h8*)&f0slab[(c8 * W_ + xe) * 8];  // f0 frag
            h2 a2[4];
            #pragma unroll
            for (int j = 0; j < 4; ++j) {
                h2 t; t.x = af[2 * j]; t.y = af[2 * j + 1];
                a2[j] = t;
            }
            const _Float16* rp = &myslab[c8 * W_ * 8];
            #pragma unroll
            for (int dx = 0; dx < 7; ++dx) {
                const h8 t = *(const h8*)&rp[xt[dx] * 8];           // tap b128
                h2 t01, t23, t45, t67;
                t01.x = t[0]; t01.y = t[1];
                t23.x = t[2]; t23.y = t[3];
                t45.x = t[4]; t45.y = t[5];
                t67.x = t[6]; t67.y = t[7];
                float s = acc[dx];
                s = FDOT2(a2[0], t01, s);
                s = FDOT2(a2[1], t23, s);
                s = FDOT2(a2[2], t45, s);
                s = FDOT2(a2[3], t67, s);
                acc[dx] = s;
            }
        }

        if (x < W_) {
            #pragma unroll
            for (int dx = 0; dx < 7; ++dx)
                corr[x][w * 7 + dx] = acc[dx] * 0.125f;   // 1/sqrt(64)
        }
    }

    __syncthreads();

    // Wave 0: per-lane softmax over 49 taps + expected flow (registers only)
    if (w == 0) {
        float c[49];
        float m = -1e30f;
        #pragma unroll
        for (int k = 0; k < 49; ++k) {
            const int kdy = k / 7, kdx = k % 7;
            const int col = x + kdx - 3;
            const int rr  = y + kdy - 3;
            const bool ok = (col >= 0) && (col < W_) && (rr >= 0) && (rr < H_);
            const float v = ok ? corr[xe][k] : -1e30f;    // mask invalid taps
            c[k] = v;
            m = fmaxf(m, v);
        }
        float S = 0.0f, Sx = 0.0f, Sy = 0.0f;
        #pragma unroll
        for (int k = 0; k < 49; ++k) {
            const float e = __expf(c[k] - m);             // -1e30 -> 0
            S  += e;
            Sx += e * (float)(k % 7 - 3);
            Sy += e * (float)(k / 7 - 3);
        }
        if (lane < W_) {
            const float inv = 1.0f / S;
            // out layout: (n, 2, s, h, w)
            const int ob = (n_idx * 2) * S_ * HW_ + s_idx * HW_ + y * W_ + lane;
            out[ob]            = Sx * inv;                // flow x
            out[ob + S_ * HW_] = Sy * inv;                // flow y
        }
    }
}

extern "C" void kernel_launch(void* const* d_in, const int* in_sizes, int n_in,
                              void* d_out, int out_size, void* d_ws, size_t ws_size,
                              hipStream_t stream) {
    const float* f0 = (const float*)d_in[0];
    const float* f1 = (const float*)d_in[1];
    float* out = (float*)d_out;

    flow_kernel<<<8 * H_, 512, 0, stream>>>(f0, f1, out);  // 512 blocks x 8 waves
}

// Round 9
// 66.004 us; speedup vs baseline: 1.0614x; 1.0033x over previous
//
#include <hip/hip_runtime.h>
#include <math.h>

// Problem constants (from reference setup_inputs)
#define N_  2
#define C_  64
#define S_  4
#define H_  64
#define W_  44
#define HW_       (H_ * W_)          // 2816
#define CH_STRIDE (S_ * HW_)         // 11264 elements between channels
#define NSTRIDE   (C_ * S_ * HW_)    // 720896 elements between n-batches

typedef _Float16 h8 __attribute__((ext_vector_type(8)));
typedef float    f4 __attribute__((ext_vector_type(4)));

// Round 9: MFMA dot engine.
// Block = (b, y), 512 threads = 8 waves, lane = x-ish.
//   waves 0..6: stage f1 row y+w-3 into slabF1[w]: f16 [c8][xi<64][8ch],
//               xi = col+8 (zero halo both sides -> MFMA needs no masking)
//   wave 7:     stage f0 row y into slabF0: f16 [c8][x<48][8ch] (zero-pad 44..47)
// One barrier, then per wave w<7: corr[x, col] = sum_ch f0[ch,x]*f1row[ch,col]
// via 12 v_mfma_f32_16x16x32_f16 (3 M-tiles x 2 N-halves x 2 K-halves):
//   A[m=lane&15][k=quad*8+j]  = slabF0 b128 at x = m0+l16      (m89/m120 layout)
//   B[k=quad*8+j][n=lane&15]  = slabF1 b128 at xi = m0+nh*16+l16
//   D row m = quad*4+reg, col n = l16  ->  band (|col-x|<=3) stored to corr
// LDS dot-phase traffic: ~126 b128 reads + 84 MFMA per block (was ~512 b128
// + 1568 v_dot2). Staging (one HBM round-trip) becomes the critical path.
__global__ __launch_bounds__(512) void flow_kernel(
    const float* __restrict__ f0,
    const float* __restrict__ f1,
    float* __restrict__ out)
{
    const int lane = threadIdx.x & 63;
    const int w    = threadIdx.x >> 6;          // 0..7

    // b = blockIdx & 7: batch pinned per XCD slot for L2 locality
    const int b = blockIdx.x & 7;
    const int y = blockIdx.x >> 3;
    const int n_idx = b >> 2;
    const int s_idx = b & 3;
    const int base  = n_idx * NSTRIDE + s_idx * HW_;

    __shared__ __align__(16) _Float16 slabF1[7 * 8 * 64 * 8];  // 57344 B
    __shared__ __align__(16) _Float16 slabF0[8 * 48 * 8];      //  6144 B
    __shared__ float corr[W_][49];                             //  8624 B

    const int row     = y + w - 3;                 // staging row for w<7
    const bool row_ok = (row >= 0) && (row < H_);

    // ---- Phase 1: stage (one global round-trip per wave) ----
    if (w < 7) {
        if (row_ok) {
            const int col   = lane - 8;            // xi = lane, col = xi-8
            const bool vld  = (col >= 0) && (col < W_);
            const int cc    = min(max(col, 0), W_ - 1);
            const float* p  = f1 + base + row * W_ + cc;
            float v[64];
            #pragma unroll
            for (int j = 0; j < 64; ++j)           // all issued before any wait
                v[j] = p[(size_t)j * CH_STRIDE];
            #pragma unroll
            for (int c8 = 0; c8 < 8; ++c8) {
                h8 pk;
                #pragma unroll
                for (int j = 0; j < 8; ++j)
                    pk[j] = vld ? (_Float16)v[c8 * 8 + j] : (_Float16)0.0f;
                *(h8*)&slabF1[((w * 8 + c8) * 64 + lane) * 8] = pk;
            }
        }
    } else {
        if (lane < 48) {                           // x = lane, zero-pad 44..47
            const bool vld = (lane < W_);
            const int  xc  = min(lane, W_ - 1);
            const float* p = f0 + base + y * W_ + xc;
            float v[64];
            #pragma unroll
            for (int j = 0; j < 64; ++j)
                v[j] = p[(size_t)j * CH_STRIDE];
            #pragma unroll
            for (int c8 = 0; c8 < 8; ++c8) {
                h8 pk;
                #pragma unroll
                for (int j = 0; j < 8; ++j)
                    pk[j] = vld ? (_Float16)v[c8 * 8 + j] : (_Float16)0.0f;
                *(h8*)&slabF0[(c8 * 48 + lane) * 8] = pk;
            }
        }
    }

    __syncthreads();   // all rows + f0 staged

    // ---- Phase 2: MFMA band GEMM (waves 0..6 with valid rows) ----
    if (w < 7 && row_ok) {
        const int quad = lane >> 4;
        const int l16  = lane & 15;

        // A fragments: f0, per (m-tile, k-half)
        h8 afr[3][2];
        #pragma unroll
        for (int mi = 0; mi < 3; ++mi)
            #pragma unroll
            for (int kh = 0; kh < 2; ++kh)
                afr[mi][kh] = *(const h8*)
                    &slabF0[((kh * 4 + quad) * 48 + (mi * 16 + l16)) * 8];

        const _Float16* myslab = &slabF1[w * (8 * 64 * 8)];
        f4 acc[3][2];
        #pragma unroll
        for (int mi = 0; mi < 3; ++mi) {
            #pragma unroll
            for (int nh = 0; nh < 2; ++nh) {
                f4 a = {0.f, 0.f, 0.f, 0.f};
                #pragma unroll
                for (int kh = 0; kh < 2; ++kh) {
                    const h8 bfr = *(const h8*)
                        &myslab[((kh * 4 + quad) * 64 + (mi * 16 + nh * 16 + l16)) * 8];
                    a = __builtin_amdgcn_mfma_f32_16x16x32_f16(afr[mi][kh], bfr, a, 0, 0, 0);
                }
                acc[mi][nh] = a;
            }
        }

        // band extraction: D[m=x][n=col], keep |col-x|<=3 -> corr[x][w*7+dx]
        #pragma unroll
        for (int mi = 0; mi < 3; ++mi) {
            #pragma unroll
            for (int nh = 0; nh < 2; ++nh) {
                #pragma unroll
                for (int r = 0; r < 4; ++r) {
                    const int x   = mi * 16 + quad * 4 + r;
                    const int col = mi * 16 + nh * 16 - 8 + l16;
                    const int dx  = col - x + 3;
                    if (x < W_ && dx >= 0 && dx < 7)
                        corr[x][w * 7 + dx] = acc[mi][nh][r] * 0.125f;  // 1/sqrt(64)
                }
            }
        }
    }

    __syncthreads();

    // ---- Phase 3: wave 0 softmax over 49 taps + expected flow ----
    if (w == 0) {
        const int xe = min(lane, W_ - 1);
        float c[49];
        float m = -1e30f;
        #pragma unroll
        for (int k = 0; k < 49; ++k) {
            const int kdy = k / 7, kdx = k % 7;
            const int col = lane + kdx - 3;
            const int rr  = y + kdy - 3;
            const bool ok = (col >= 0) && (col < W_) && (rr >= 0) && (rr < H_);
            const float v = ok ? corr[xe][k] : -1e30f;    // mask invalid taps
            c[k] = v;
            m = fmaxf(m, v);
        }
        float S = 0.0f, Sx = 0.0f, Sy = 0.0f;
        #pragma unroll
        for (int k = 0; k < 49; ++k) {
            const float e = __expf(c[k] - m);             // -1e30 -> 0
            S  += e;
            Sx += e * (float)(k % 7 - 3);
            Sy += e * (float)(k / 7 - 3);
        }
        if (lane < W_) {
            const float inv = 1.0f / S;
            // out layout: (n, 2, s, h, w)
            const int ob = (n_idx * 2) * S_ * HW_ + s_idx * HW_ + y * W_ + lane;
            out[ob]            = Sx * inv;                // flow x
            out[ob + S_ * HW_] = Sy * inv;                // flow y
        }
    }
}

extern "C" void kernel_launch(void* const* d_in, const int* in_sizes, int n_in,
                              void* d_out, int out_size, void* d_ws, size_t ws_size,
                              hipStream_t stream) {
    const float* f0 = (const float*)d_in[0];
    const float* f1 = (const float*)d_in[1];
    float* out = (float*)d_out;

    flow_kernel<<<8 * H_, 512, 0, stream>>>(f0, f1, out);  // 512 blocks x 8 waves
}